// Round 5
// baseline (1216.941 us; speedup 1.0000x reference)
//
#include <hip/hip_runtime.h>

#define NUM_USERS 100000
#define NUM_ITEMS 50000
#define N_NODES   150000   // NUM_USERS + NUM_ITEMS
#define DIM       64
#define NUM_EDGES 2000000
#define NXCD      8
#define COLS_PER_GRP ((N_NODES + NXCD - 1) / NXCD)   // 18750

#define SCAN_THREADS 256
#define SCAN_ITEMS   8
#define SCAN_CHUNK   (SCAN_THREADS * SCAN_ITEMS)          // 2048
#define SCAN_NBLK    ((N_NODES + SCAN_CHUNK - 1) / SCAN_CHUNK)  // 74

// ---------------------------------------------------------------------------
// integer degree histogram over col
__global__ void deghist_kernel(const int* __restrict__ col,
                               int* __restrict__ deg, int nE) {
    int stride = gridDim.x * blockDim.x;
    for (int e = blockIdx.x * blockDim.x + threadIdx.x; e < nE; e += stride)
        atomicAdd(&deg[col[e]], 1);
}

// dinv[i] = deg>0 ? 1/sqrt(deg) : 0
__global__ void dinv_kernel(const int* __restrict__ deg,
                            float* __restrict__ dinv, int n) {
    int stride = gridDim.x * blockDim.x;
    for (int i = blockIdx.x * blockDim.x + threadIdx.x; i < n; i += stride) {
        float d = (float)deg[i];
        dinv[i] = (d > 0.0f) ? (1.0f / sqrtf(d)) : 0.0f;
    }
}

// ---- exclusive scan of deg -> col_ptr (3 kernels) ----
__global__ void scanA_kernel(const int* __restrict__ deg,
                             int* __restrict__ colptr,
                             int* __restrict__ bsum) {
    __shared__ int s[SCAN_THREADS];
    int t = threadIdx.x;
    int base = blockIdx.x * SCAN_CHUNK + t * SCAN_ITEMS;
    int items[SCAN_ITEMS];
    int mysum = 0;
    #pragma unroll
    for (int j = 0; j < SCAN_ITEMS; ++j) {
        int idx = base + j;
        items[j] = (idx < N_NODES) ? deg[idx] : 0;
        mysum += items[j];
    }
    s[t] = mysum;
    __syncthreads();
    for (int off = 1; off < SCAN_THREADS; off <<= 1) {
        int v = (t >= off) ? s[t - off] : 0;
        __syncthreads();
        s[t] += v;
        __syncthreads();
    }
    int excl = s[t] - mysum;
    if (t == SCAN_THREADS - 1) bsum[blockIdx.x] = s[t];
    int run = excl;
    #pragma unroll
    for (int j = 0; j < SCAN_ITEMS; ++j) {
        int idx = base + j;
        if (idx < N_NODES) colptr[idx] = run;
        run += items[j];
    }
}

__global__ void scanB_kernel(int* __restrict__ bsum,
                             int* __restrict__ boff,
                             int* __restrict__ colptr) {
    if (threadIdx.x == 0) {
        int run = 0;
        for (int b = 0; b < SCAN_NBLK; ++b) {
            boff[b] = run;
            run += bsum[b];
        }
        colptr[N_NODES] = run;
    }
}

__global__ void scanC_kernel(int* __restrict__ colptr,
                             int* __restrict__ cursor,
                             const int* __restrict__ boff) {
    int t = threadIdx.x;
    int off = boff[blockIdx.x];
    int base = blockIdx.x * SCAN_CHUNK + t * SCAN_ITEMS;
    #pragma unroll
    for (int j = 0; j < SCAN_ITEMS; ++j) {
        int idx = base + j;
        if (idx < N_NODES) {
            int v = colptr[idx] + off;
            colptr[idx] = v;
            cursor[idx] = v;
        }
    }
}

// bucket edges by col, XCD-local: group g = blockIdx&7 handles cols in
// [g*COLS_PER_GRP, ...). Its EDATA slice (~2MB) + cursor slice (~75KB) stay
// resident in that XCD's private L2 -> writes stop thrashing to HBM.
// Correctness does NOT depend on the block->XCD mapping (perf heuristic only).
__global__ void edgescatter_kernel(const int* __restrict__ row,
                                   const int* __restrict__ col,
                                   const float* __restrict__ dinv,
                                   int* __restrict__ cursor,
                                   int2* __restrict__ edata, int nE) {
    int grp = blockIdx.x & (NXCD - 1);
    int blkInGrp = blockIdx.x >> 3;
    int nBlkGrp = gridDim.x >> 3;
    int lo = grp * COLS_PER_GRP;
    int hi = lo + COLS_PER_GRP; if (hi > N_NODES) hi = N_NODES;
    int stride = nBlkGrp * blockDim.x;
    for (int e = blkInGrp * blockDim.x + threadIdx.x; e < nE; e += stride) {
        int c = col[e];
        if (c >= lo && c < hi) {
            int r = row[e];
            int p = atomicAdd(&cursor[c], 1);
            edata[p] = make_int2(r, __float_as_int(dinv[r] * dinv[c]));
        }
    }
}

// ---------------------------------------------------------------------------
// CSR gather conv, 4 edges in flight per wave.
// Wave = one node. 4 groups of 16 lanes; group g handles edges s+g, s+g+4, ...
// Each group holds the full 64-dim accumulator as 16 lanes x float4.
// Cross-group reduce via shfl_xor(16), shfl_xor(32); group 0 writes.
// MODE 0: out = sum ; MODE 1: out = (a0+a1+sum)/3 ; MODE 2: out = a2+(a0+a1+sum)/3
template <int MODE>
__global__ void conv_kernel(const float4* __restrict__ xin,
                            const int* __restrict__ colptr,
                            const int2* __restrict__ edata,
                            const float4* __restrict__ a0,
                            const float4* __restrict__ a1,
                            const float4* __restrict__ a2,
                            float4* __restrict__ out) {
    int lane = threadIdx.x & 63;
    int node = (blockIdx.x * blockDim.x + threadIdx.x) >> 6;
    if (node >= N_NODES) return;
    int grp = lane >> 4;          // 0..3 edge slot
    int l16 = lane & 15;          // float4 index within the 64-dim row
    int s = colptr[node];
    int t = colptr[node + 1];
    float4 acc = make_float4(0.0f, 0.0f, 0.0f, 0.0f);
    for (int e = s + grp; e < t; e += 4) {
        int2 ed = edata[e];                       // broadcast within 16-lane group
        float nm = __int_as_float(ed.y);
        float4 v = xin[ed.x * 16 + l16];          // 16 lanes x 16B = 256B gather
        acc.x = fmaf(v.x, nm, acc.x);
        acc.y = fmaf(v.y, nm, acc.y);
        acc.z = fmaf(v.z, nm, acc.z);
        acc.w = fmaf(v.w, nm, acc.w);
    }
    // combine the 4 groups' partial sums
    acc.x += __shfl_xor(acc.x, 16); acc.y += __shfl_xor(acc.y, 16);
    acc.z += __shfl_xor(acc.z, 16); acc.w += __shfl_xor(acc.w, 16);
    acc.x += __shfl_xor(acc.x, 32); acc.y += __shfl_xor(acc.y, 32);
    acc.z += __shfl_xor(acc.z, 32); acc.w += __shfl_xor(acc.w, 32);
    if (grp == 0) {
        int o = node * 16 + l16;
        if (MODE == 0) {
            out[o] = acc;
        } else if (MODE == 1) {
            float4 p = a0[o], q = a1[o];
            const float sc = 1.0f / 3.0f;
            out[o] = make_float4((p.x + q.x + acc.x) * sc,
                                 (p.y + q.y + acc.y) * sc,
                                 (p.z + q.z + acc.z) * sc,
                                 (p.w + q.w + acc.w) * sc);
        } else {
            float4 p = a0[o], q = a1[o], g = a2[o];
            const float sc = 1.0f / 3.0f;
            out[o] = make_float4(g.x + (p.x + q.x + acc.x) * sc,
                                 g.y + (p.y + q.y + acc.y) * sc,
                                 g.z + (p.z + q.z + acc.z) * sc,
                                 g.w + (p.w + q.w + acc.w) * sc);
        }
    }
}

// Wt[k][j] = W[j][k] for both weight matrices (single block)
__global__ void transpose_w_kernel(const float* __restrict__ Wu,
                                   const float* __restrict__ Wi,
                                   float* __restrict__ WtU,
                                   float* __restrict__ WtI) {
    for (int t = threadIdx.x; t < DIM * DIM; t += blockDim.x) {
        int j = t >> 6, k = t & 63;
        WtU[k * DIM + j] = Wu[t];
        WtI[k * DIM + j] = Wi[t];
    }
}

// dst[i][j] = sum_k src[i][k] * Wt[k][j], Wt chosen per row (user vs item)
__global__ void matmul_kernel(const float* __restrict__ src,
                              const float* __restrict__ WtU,
                              const float* __restrict__ WtI,
                              float* __restrict__ dst) {
    __shared__ float rows[4][DIM];
    int lane = threadIdx.x & 63;
    int g = threadIdx.x >> 6;
    int totalGroups = N_NODES / 4;
    for (int blk = blockIdx.x; blk < totalGroups; blk += gridDim.x) {
        int i = blk * 4 + g;
        rows[g][lane] = src[(size_t)i * DIM + lane];
        __syncthreads();
        const float* Wt = (i < NUM_USERS) ? WtU : WtI;
        float acc = 0.0f;
        #pragma unroll
        for (int k = 0; k < DIM; ++k)
            acc = fmaf(rows[g][k], Wt[k * DIM + lane], acc);
        dst[(size_t)i * DIM + lane] = acc;
        __syncthreads();
    }
}

// ---------------------------------------------------------------------------
extern "C" void kernel_launch(void* const* d_in, const int* in_sizes, int n_in,
                              void* d_out, int out_size, void* d_ws, size_t ws_size,
                              hipStream_t stream) {
    const float* user_emb = (const float*)d_in[0];
    const float* item_emb = (const float*)d_in[1];
    const float* W_user   = (const float*)d_in[2];
    const float* W_item   = (const float*)d_in[3];
    const int*   ec       = (const int*)d_in[4];   // [2][NUM_EDGES]
    const int*   er       = (const int*)d_in[5];
    const int* cart_row = ec;
    const int* cart_col = ec + NUM_EDGES;
    const int* rent_row = er;
    const int* rent_col = er + NUM_EDGES;
    float* out = (float*)d_out;

    const size_t NV = (size_t)N_NODES * DIM;       // 9.6M floats
    float* ws    = (float*)d_ws;
    float* X     = ws;                  // node features / rent_init
    float* H1    = X    + NV;
    float* CART  = H1   + NV;
    float* DINV  = CART + NV;
    int*   DEG   = (int*)(DINV + 150016);
    int*   CPTR  = DEG  + 150016;
    int*   CURS  = CPTR + 150016;
    int*   BSUM  = CURS + 150016;
    int*   BOFF  = BSUM + 128;
    float* WtU   = (float*)(BOFF + 128);
    float* WtI   = WtU + DIM * DIM;
    int2*  EDATA = (int2*)(WtI + DIM * DIM);       // 2M int2 = 16 MB

    const int BLOCKS = 2048, THREADS = 256;
    const int ES_BLOCKS = 256;                     // 8 groups x 32 blocks
    const int CONV_BLOCKS = (N_NODES + 3) / 4;     // 4 waves (nodes) per block

    // x0 = concat(user_emb, item_emb)
    hipMemcpyAsync(X, user_emb, (size_t)NUM_USERS * DIM * sizeof(float),
                   hipMemcpyDeviceToDevice, stream);
    hipMemcpyAsync(X + (size_t)NUM_USERS * DIM, item_emb,
                   (size_t)NUM_ITEMS * DIM * sizeof(float),
                   hipMemcpyDeviceToDevice, stream);
    transpose_w_kernel<<<1, 256, 0, stream>>>(W_user, W_item, WtU, WtI);

    // ================= behavior 1: cart =================
    hipMemsetAsync(DEG, 0, N_NODES * sizeof(int), stream);
    deghist_kernel<<<BLOCKS, THREADS, 0, stream>>>(cart_col, DEG, NUM_EDGES);
    dinv_kernel<<<(N_NODES + 255) / 256, 256, 0, stream>>>(DEG, DINV, N_NODES);
    scanA_kernel<<<SCAN_NBLK, SCAN_THREADS, 0, stream>>>(DEG, CPTR, BSUM);
    scanB_kernel<<<1, 64, 0, stream>>>(BSUM, BOFF, CPTR);
    scanC_kernel<<<SCAN_NBLK, SCAN_THREADS, 0, stream>>>(CPTR, CURS, BOFF);
    edgescatter_kernel<<<ES_BLOCKS, THREADS, 0, stream>>>(cart_row, cart_col, DINV,
                                                          CURS, EDATA, NUM_EDGES);

    // layer 1: H1 = conv(X); layer 2 fused with combine: CART = (X+H1+conv(H1))/3
    conv_kernel<0><<<CONV_BLOCKS, 256, 0, stream>>>((const float4*)X, CPTR, EDATA,
                                                    nullptr, nullptr, nullptr,
                                                    (float4*)H1);
    conv_kernel<1><<<CONV_BLOCKS, 256, 0, stream>>>((const float4*)H1, CPTR, EDATA,
                                                    (const float4*)X, (const float4*)H1,
                                                    nullptr, (float4*)CART);

    // ---- projection: X = CART @ W^T (per-row user/item) ----
    matmul_kernel<<<BLOCKS, THREADS, 0, stream>>>(CART, WtU, WtI, X);

    // ================= behavior 2: rent =================
    hipMemsetAsync(DEG, 0, N_NODES * sizeof(int), stream);
    deghist_kernel<<<BLOCKS, THREADS, 0, stream>>>(rent_col, DEG, NUM_EDGES);
    dinv_kernel<<<(N_NODES + 255) / 256, 256, 0, stream>>>(DEG, DINV, N_NODES);
    scanA_kernel<<<SCAN_NBLK, SCAN_THREADS, 0, stream>>>(DEG, CPTR, BSUM);
    scanB_kernel<<<1, 64, 0, stream>>>(BSUM, BOFF, CPTR);
    scanC_kernel<<<SCAN_NBLK, SCAN_THREADS, 0, stream>>>(CPTR, CURS, BOFF);
    edgescatter_kernel<<<ES_BLOCKS, THREADS, 0, stream>>>(rent_row, rent_col, DINV,
                                                          CURS, EDATA, NUM_EDGES);

    // layer 1: H1 = conv(X); layer 2 fused with final: out = CART + (X+H1+conv(H1))/3
    conv_kernel<0><<<CONV_BLOCKS, 256, 0, stream>>>((const float4*)X, CPTR, EDATA,
                                                    nullptr, nullptr, nullptr,
                                                    (float4*)H1);
    conv_kernel<2><<<CONV_BLOCKS, 256, 0, stream>>>((const float4*)H1, CPTR, EDATA,
                                                    (const float4*)X, (const float4*)H1,
                                                    (const float4*)CART, (float4*)out);
}